// Round 4
// baseline (939.134 us; speedup 1.0000x reference)
//
#include <hip/hip_runtime.h>
#include <math.h>

#define NCLS 16
#define DIM  64

// ---------------- K1a: init counters + Gram buffer ----------------
__global__ void k_init(int* __restrict__ cnt, float* __restrict__ G) {
    int t = blockIdx.x * blockDim.x + threadIdx.x;
    if (t < NCLS) cnt[t] = 0;
    for (int i = t; i < NCLS * DIM * DIM; i += gridDim.x * blockDim.x) G[i] = 0.f;
}

// ---------------- K1b: class histogram (16x sub-banked LDS) ----------------
__global__ void k_hist(const int* __restrict__ label, int n, int* __restrict__ cnt) {
    __shared__ int h[NCLS * 16];
    for (int i = threadIdx.x; i < NCLS * 16; i += 256) h[i] = 0;
    __syncthreads();
    const int sub = threadIdx.x & 15;
    int stride = gridDim.x * blockDim.x;
    for (int i = blockIdx.x * blockDim.x + threadIdx.x; i < n; i += stride)
        atomicAdd(&h[label[i] * 16 + sub], 1);
    __syncthreads();
    if (threadIdx.x < NCLS) {
        int s = 0;
#pragma unroll
        for (int j = 0; j < 16; j++) s += h[threadIdx.x * 16 + j];
        atomicAdd(&cnt[threadIdx.x], s);
    }
}

// ---------------- K1c: tiny exclusive scan ----------------
__global__ void k_scan(const int* __restrict__ cnt, int* __restrict__ base,
                       int* __restrict__ cursor) {
    if (threadIdx.x == 0) {
        int s = 0;
        for (int c = 0; c < NCLS; c++) { base[c] = s; cursor[c] = s; s += cnt[c]; }
    }
}

// ---------------- K1d: scatter (16x sub-banked cursors; exact reservation) ---
__global__ void k_scatter(const int* __restrict__ label, int n,
                          int* __restrict__ cursor, int* __restrict__ idx) {
    __shared__ int h[NCLS * 16];
    __shared__ int cur[NCLS * 16];
    for (int i = threadIdx.x; i < NCLS * 16; i += 256) h[i] = 0;
    __syncthreads();
    const int sub = threadIdx.x & 15;
    int stride = gridDim.x * blockDim.x;
    for (int i = blockIdx.x * blockDim.x + threadIdx.x; i < n; i += stride)
        atomicAdd(&h[label[i] * 16 + sub], 1);
    __syncthreads();
    for (int e = threadIdx.x; e < NCLS * 16; e += 256)
        cur[e] = atomicAdd(&cursor[e >> 4], h[e]);
    __syncthreads();
    for (int i = blockIdx.x * blockDim.x + threadIdx.x; i < n; i += stride) {
        int p = atomicAdd(&cur[label[i] * 16 + sub], 1);
        idx[p] = i;
    }
}

// ---------------- K2: per-class Gram via register 8x8 tiles ----------------
// (unchanged — spill-free, __launch_bounds__(256,4), LDS block reduce)
__global__ __launch_bounds__(256, 4) void k_gram(const float* __restrict__ feat,
                                                 const int* __restrict__ idx,
                                                 const int* __restrict__ base,
                                                 const int* __restrict__ cnt,
                                                 float* __restrict__ G) {
    const int c    = blockIdx.x & (NCLS - 1);
    const int blk  = blockIdx.x >> 4;
    const int wave = threadIdx.x >> 6;
    const int lane = threadIdx.x & 63;
    const int gw   = blk * 4 + wave;
    const int r0   = (lane >> 3) << 3;
    const int c0   = (lane & 7) << 3;
    const int m    = cnt[c];
    const int b0   = base[c];
    const int STEP = 256 * 2;

    float acc[8][8];
#pragma unroll
    for (int j = 0; j < 8; j++)
#pragma unroll
        for (int k = 0; k < 8; k++) acc[j][k] = 0.f;

    int ii[2];
    const int p0 = gw * 2;
#pragma unroll
    for (int q = 0; q < 2; q++) ii[q] = (p0 + q < m) ? idx[b0 + p0 + q] : -1;

    for (int p = p0; p < m; p += STEP) {
        float4 xa[2][2], xb[2][2];
#pragma unroll
        for (int q = 0; q < 2; q++) {
            if (ii[q] >= 0) {
                const float* rp = feat + (size_t)ii[q] * DIM;
                xa[q][0] = *(const float4*)(rp + r0);
                xa[q][1] = *(const float4*)(rp + r0 + 4);
                xb[q][0] = *(const float4*)(rp + c0);
                xb[q][1] = *(const float4*)(rp + c0 + 4);
            } else {
                float4 z = make_float4(0.f, 0.f, 0.f, 0.f);
                xa[q][0] = z; xa[q][1] = z; xb[q][0] = z; xb[q][1] = z;
            }
        }
        const int pn = p + STEP;
#pragma unroll
        for (int q = 0; q < 2; q++) ii[q] = (pn + q < m) ? idx[b0 + pn + q] : -1;

#pragma unroll
        for (int q = 0; q < 2; q++) {
            float av[8] = {xa[q][0].x, xa[q][0].y, xa[q][0].z, xa[q][0].w,
                           xa[q][1].x, xa[q][1].y, xa[q][1].z, xa[q][1].w};
            float bv[8] = {xb[q][0].x, xb[q][0].y, xb[q][0].z, xb[q][0].w,
                           xb[q][1].x, xb[q][1].y, xb[q][1].z, xb[q][1].w};
#pragma unroll
            for (int j = 0; j < 8; j++)
#pragma unroll
                for (int k = 0; k < 8; k++)
                    acc[j][k] = fmaf(av[j], bv[k], acc[j][k]);
        }
    }

    __shared__ float tile[DIM * DIM];
    for (int w = 0; w < 4; w++) {
        if (wave == w) {
            float* t = tile + r0 * DIM + c0;
            if (w == 0) {
#pragma unroll
                for (int j = 0; j < 8; j++) {
                    *(float4*)(t + j * DIM)     = make_float4(acc[j][0], acc[j][1], acc[j][2], acc[j][3]);
                    *(float4*)(t + j * DIM + 4) = make_float4(acc[j][4], acc[j][5], acc[j][6], acc[j][7]);
                }
            } else {
#pragma unroll
                for (int j = 0; j < 8; j++) {
                    float4 u0 = *(float4*)(t + j * DIM);
                    float4 u1 = *(float4*)(t + j * DIM + 4);
                    u0.x += acc[j][0]; u0.y += acc[j][1]; u0.z += acc[j][2]; u0.w += acc[j][3];
                    u1.x += acc[j][4]; u1.y += acc[j][5]; u1.z += acc[j][6]; u1.w += acc[j][7];
                    *(float4*)(t + j * DIM)     = u0;
                    *(float4*)(t + j * DIM + 4) = u1;
                }
            }
        }
        __syncthreads();
    }
    float* g = G + c * DIM * DIM;
    for (int e = threadIdx.x; e < DIM * DIM; e += 256)
        atomicAdd(&g[e], tile[e]);
}

// ---------------- K3: top eigenvector per class (v3: 4-wave cooperative) ----
// 256 threads per class. Same math as v2 (trace-moment shift, 7 squarings of
// (G - sigma I) -> C = shifted^128, column-of-max-diag start, 8 applies), but
// no thread holds a 64-float array (v2's 68-VGPR alloc spilled row[]/h[]) and
// each squaring is a 4-wave output-split matmul on double-buffered LDS:
// wave w computes rows [16w,16w+16), lane holds a 2x8 accumulator (16 VGPRs).
// Operands come from row k via symmetry (A[k][r], A[k][c]) -> exact symmetry
// of every iterate is preserved (both operands read from the same row).
__global__ __launch_bounds__(256, 1) void k_eig(const float* __restrict__ G,
                                                float* __restrict__ V) {
    const int c    = blockIdx.x;
    const int t    = threadIdx.x;
    const int wave = t >> 6;
    const int lane = t & 63;
    __shared__ float shA[DIM * DIM];
    __shared__ float shB[DIM * DIM];
    __shared__ float shP[4 * DIM];
    __shared__ float shRed[4];
    __shared__ float shV[DIM];

    // ---- load G (coalesced, 4 float4 per thread) ----
    {
        const float4* g4 = (const float4*)(G + c * DIM * DIM);
        float4* a4 = (float4*)shA;
#pragma unroll
        for (int j = 0; j < 4; j++) a4[t + 256 * j] = g4[t + 256 * j];
    }
    __syncthreads();

    // ---- trace moments: s2 = sum A_ij^2 (all 256 threads), trace (wave 0) ----
    float ss = 0.f;
    {
        const float4* a4 = (const float4*)shA;
#pragma unroll
        for (int j = 0; j < 4; j++) {
            float4 x = a4[t + 256 * j];
            ss = fmaf(x.x, x.x, fmaf(x.y, x.y, fmaf(x.z, x.z, fmaf(x.w, x.w, ss))));
        }
    }
#pragma unroll
    for (int m = 1; m < 64; m <<= 1) ss += __shfl_xor(ss, m);
    if (lane == 0) shRed[wave] = ss;
    __syncthreads();
    if (wave == 0) {
        float s2 = shRed[0] + shRed[1] + shRed[2] + shRed[3];
        float d  = shA[lane * 65];
        float sd = d;
#pragma unroll
        for (int m = 1; m < 64; m <<= 1) sd += __shfl_xor(sd, m);
        float mu    = sd * (1.f / 64.f);
        float var   = fmaxf(s2 * (1.f / 64.f) - mu * mu, 0.f);
        float sigma = mu - 0.2f * sqrtf(var);   // MP edges ~ mu +/- 2*sd
        shA[lane * 65] = d - sigma;
    }
    __syncthreads();

    // ---- 7 squarings, double-buffered ----
    float* cur = shA;
    float* nxt = shB;
    const int ra = wave * 16 + ((lane >> 3) << 1);  // this lane's 2 output rows
    const int c0 = (lane & 7) << 3;                 // this lane's 8 output cols
    for (int sq = 0; sq < 7; sq++) {
        float acc[2][8];
#pragma unroll
        for (int j = 0; j < 8; j++) { acc[0][j] = 0.f; acc[1][j] = 0.f; }
#pragma unroll 4
        for (int k = 0; k < DIM; k++) {
            const float* rk = cur + k * DIM;
            float2 a2 = *(const float2*)(rk + ra);   // A[k][ra], A[k][ra+1]
            float4 b0 = *(const float4*)(rk + c0);   // A[k][c0..c0+3]
            float4 b1 = *(const float4*)(rk + c0 + 4);
            acc[0][0] = fmaf(a2.x, b0.x, acc[0][0]);
            acc[0][1] = fmaf(a2.x, b0.y, acc[0][1]);
            acc[0][2] = fmaf(a2.x, b0.z, acc[0][2]);
            acc[0][3] = fmaf(a2.x, b0.w, acc[0][3]);
            acc[0][4] = fmaf(a2.x, b1.x, acc[0][4]);
            acc[0][5] = fmaf(a2.x, b1.y, acc[0][5]);
            acc[0][6] = fmaf(a2.x, b1.z, acc[0][6]);
            acc[0][7] = fmaf(a2.x, b1.w, acc[0][7]);
            acc[1][0] = fmaf(a2.y, b0.x, acc[1][0]);
            acc[1][1] = fmaf(a2.y, b0.y, acc[1][1]);
            acc[1][2] = fmaf(a2.y, b0.z, acc[1][2]);
            acc[1][3] = fmaf(a2.y, b0.w, acc[1][3]);
            acc[1][4] = fmaf(a2.y, b1.x, acc[1][4]);
            acc[1][5] = fmaf(a2.y, b1.y, acc[1][5]);
            acc[1][6] = fmaf(a2.y, b1.z, acc[1][6]);
            acc[1][7] = fmaf(a2.y, b1.w, acc[1][7]);
        }
        // write to the other buffer (no reader conflict; readers use cur)
        *(float4*)(nxt + (ra + 0) * DIM + c0)     = make_float4(acc[0][0], acc[0][1], acc[0][2], acc[0][3]);
        *(float4*)(nxt + (ra + 0) * DIM + c0 + 4) = make_float4(acc[0][4], acc[0][5], acc[0][6], acc[0][7]);
        *(float4*)(nxt + (ra + 1) * DIM + c0)     = make_float4(acc[1][0], acc[1][1], acc[1][2], acc[1][3]);
        *(float4*)(nxt + (ra + 1) * DIM + c0 + 4) = make_float4(acc[1][4], acc[1][5], acc[1][6], acc[1][7]);
        __syncthreads();
        // rescale by global max|elem| to avoid overflow across squarings
        float4 xs[4];
        float mx = 0.f;
        {
            const float4* n4 = (const float4*)nxt;
#pragma unroll
            for (int j = 0; j < 4; j++) {
                float4 x = n4[t + 256 * j];
                xs[j] = x;
                mx = fmaxf(mx, fmaxf(fmaxf(fabsf(x.x), fabsf(x.y)),
                                     fmaxf(fabsf(x.z), fabsf(x.w))));
            }
        }
#pragma unroll
        for (int m = 1; m < 64; m <<= 1) mx = fmaxf(mx, __shfl_xor(mx, m));
        if (lane == 0) shRed[wave] = mx;
        __syncthreads();
        float gm = fmaxf(fmaxf(shRed[0], shRed[1]), fmaxf(shRed[2], shRed[3]));
        float inv = (gm > 0.f) ? (1.0f / gm) : 1.0f;
        {
            float4* n4 = (float4*)nxt;
#pragma unroll
            for (int j = 0; j < 4; j++) {
                float4 x = xs[j];
                n4[t + 256 * j] = make_float4(x.x * inv, x.y * inv, x.z * inv, x.w * inv);
            }
        }
        __syncthreads();
        float* tmp = cur; cur = nxt; nxt = tmp;
    }

    // ---- v0 = column with max diagonal (sign convention built in) ----
    if (wave == 0) {
        float d = cur[lane * 65];
        float dmax = d;
#pragma unroll
        for (int m = 1; m < 64; m <<= 1) dmax = fmaxf(dmax, __shfl_xor(dmax, m));
        unsigned long long bal = __ballot(d == dmax);
        int jstar = __ffsll((long long)bal) - 1;
        shV[lane] = cur[jstar * DIM + lane];   // row j* == col j* (symmetry)
    }
    __syncthreads();

    // ---- 8 polishing applies of C (growth <= 64^8, fits fp32) ----
    for (int it = 0; it < 8; it++) {
        float part = 0.f;
#pragma unroll
        for (int j = 0; j < 16; j++) {
            int k = wave * 16 + j;
            part = fmaf(cur[k * DIM + lane], shV[k], part);  // C[k][lane]*v[k]
        }
        shP[wave * DIM + lane] = part;
        __syncthreads();
        if (wave == 0)
            shV[lane] = shP[lane] + shP[64 + lane] + shP[128 + lane] + shP[192 + lane];
        __syncthreads();
    }

    // ---- normalize + sign (largest-|.| component positive) ----
    if (wave == 0) {
        float val = shV[lane];
        float nn = val * val;
#pragma unroll
        for (int m = 1; m < 64; m <<= 1) nn += __shfl_xor(nn, m);
        float inv = (nn > 1e-30f) ? rsqrtf(nn) : 1.0f;
        float am = fabsf(val);
        float bm = am;
#pragma unroll
        for (int m = 1; m < 64; m <<= 1) bm = fmaxf(bm, __shfl_xor(bm, m));
        unsigned long long bal = __ballot(am == bm);
        int jm = __ffsll((long long)bal) - 1;
        float vm = __shfl(val, jm);
        float s = (vm < 0.f) ? -inv : inv;
        V[c * DIM + lane] = val * s;
    }
}

// ---------------- K4: given[i] = <feat_i, V[label_i]> ----------------
__global__ __launch_bounds__(256) void k_out(const float* __restrict__ feat,
                                             const int* __restrict__ label,
                                             const float* __restrict__ V,
                                             float* __restrict__ out, int n) {
    int i = blockIdx.x * blockDim.x + threadIdx.x;
    if (i >= n) return;
    const float4* rp = (const float4*)(feat + (size_t)i * DIM);
    const float4* vp = (const float4*)(V + label[i] * DIM);
    float s0 = 0, s1 = 0, s2 = 0, s3 = 0;
#pragma unroll
    for (int j = 0; j < 16; j++) {
        float4 a = rp[j], b = vp[j];
        s0 = fmaf(a.x, b.x, s0);
        s1 = fmaf(a.y, b.y, s1);
        s2 = fmaf(a.z, b.z, s2);
        s3 = fmaf(a.w, b.w, s3);
    }
    out[i] = (s0 + s1) + (s2 + s3);
}

extern "C" void kernel_launch(void* const* d_in, const int* in_sizes, int n_in,
                              void* d_out, int out_size, void* d_ws, size_t ws_size,
                              hipStream_t stream) {
    const float* feat  = (const float*)d_in[0];
    const int*   label = (const int*)d_in[1];
    const int    n     = in_sizes[1];
    float*       out   = (float*)d_out;

    int*   cnt    = (int*)d_ws;
    int*   base   = cnt + 16;
    int*   cursor = cnt + 32;
    float* G      = (float*)(cnt + 64);          // 16 * 4096 floats
    float* V      = G + NCLS * DIM * DIM;        // 16 * 64 floats
    int*   idx    = (int*)(V + NCLS * DIM);      // n ints

    k_init<<<64, 256, 0, stream>>>(cnt, G);
    k_hist<<<256, 256, 0, stream>>>(label, n, cnt);
    k_scan<<<1, 64, 0, stream>>>(cnt, base, cursor);
    k_scatter<<<256, 256, 0, stream>>>(label, n, cursor, idx);
    k_gram<<<NCLS * 64, 256, 0, stream>>>(feat, idx, base, cnt, G);
    k_eig<<<NCLS, 256, 0, stream>>>(G, V);
    k_out<<<(n + 255) / 256, 256, 0, stream>>>(feat, label, V, out, n);
}